// Round 1
// baseline (5419.580 us; speedup 1.0000x reference)
//
#include <hip/hip_runtime.h>

typedef unsigned short u16;
typedef unsigned int u32;
typedef __bf16 bf16x8 __attribute__((ext_vector_type(8)));
typedef float f32x4 __attribute__((ext_vector_type(4)));
typedef u16 u16x8 __attribute__((ext_vector_type(8)));
typedef u16 u16x4 __attribute__((ext_vector_type(4)));

#define MFMA16x16(a,b,c) __builtin_amdgcn_mfma_f32_16x16x32_bf16((a),(b),(c),0,0,0)

static __device__ __forceinline__ u16 f2bf(float f){
  u32 u = __builtin_bit_cast(u32, f);
  u += 0x7fffu + ((u >> 16) & 1u);
  return (u16)(u >> 16);
}
static __device__ __forceinline__ float bf2f(u16 h){
  u32 u = ((u32)h) << 16;
  return __builtin_bit_cast(float, u);
}
static __device__ __forceinline__ float fast_sigmoid(float x){
  return 1.f / (1.f + __expf(-x));
}
static __device__ __forceinline__ float fast_tanh(float x){
  float e = __expf(2.f * x);
  return 1.f - 2.f / (e + 1.f);
}
static __device__ __forceinline__ float fast_softplus(float x){
  return (x > 15.f) ? x : __logf(1.f + __expf(x));
}
static __device__ __forceinline__ f32x4 zero4(){
  f32x4 v; v[0]=0.f; v[1]=0.f; v[2]=0.f; v[3]=0.f; return v;
}

// ---------------------------------------------------------------------------
// Weight swizzle into MFMA B-fragment order:
// dst[ks][nt][lane][j]  (u16 bf16) = W[k = ks*32 + (lane>>4)*8 + j][ncol = nt*16 + (lane&15)]
// modes: 0 enc GRU  1 dec GRU  2 post(500x500+b)  3 zW(zm/zs)  4 heads(xm/xs)
// ---------------------------------------------------------------------------
__global__ void build_frag(u16* __restrict__ dst, int mode, int KS, int NT,
                           const float* __restrict__ W0, const float* __restrict__ b0,
                           const float* __restrict__ W1, const float* __restrict__ b1)
{
  int idx = blockIdx.x * 256 + threadIdx.x;
  int total = KS * NT * 512;
  if (idx >= total) return;
  int j    = idx & 7;
  int lane = (idx >> 3) & 63;
  int ntks = idx >> 9;
  int nt   = ntks % NT;
  int ks   = ntks / NT;
  int k    = ks * 32 + ((lane >> 4) << 3) + j;
  int ncol = (nt << 4) + (lane & 15);
  float v = 0.f;
  if (mode == 0 || mode == 1){            // GRU combined: rows 0..499 Whh^T, 511 bhh, 512.. Wih^T, bias bih
    int g = ncol >> 9;
    int jin = ncol & 511;
    if (jin < 500){
      int row = g * 500 + jin;            // row of W [1500][K]
      if (k < 500) v = W0[row * 500 + k];
      else if (k == 511) v = b0[row];
      else if (mode == 0){
        if (k >= 512 && k < 550) v = W1[row * 38 + (k - 512)];
        else if (k == 550) v = b1[row];
      } else {
        if (k >= 512 && k < 515) v = W1[row * 3 + (k - 512)];
        else if (k == 515) v = b1[row];
      }
    }
  } else if (mode == 2){                  // post: W0 [500][500], bias row 511
    if (ncol < 500){
      if (k < 500) v = W0[ncol * 500 + k];
      else if (k == 511) v = b0[ncol];
    }
  } else if (mode == 3){                  // zW: cols 0..2 zm (W0 [3][503]), 3..5 zs
    int c = ncol;
    if (c < 3){
      if (k < 500) v = W0[c * 503 + k];
      else if (k == 511) v = b0[c];
    } else if (c < 6){
      int cc = c - 3;
      if (k < 500) v = W1[cc * 503 + k];
      else if (k == 511) v = b1[cc];
    }
  } else {                                // heads: cols 0..47 xm (valid<38), 48..95 xs
    int grp = ncol / 48;
    int cc  = ncol - grp * 48;
    if (grp < 2 && cc < 38){
      const float* W  = grp ? W1 : W0;
      const float* bb = grp ? b1 : b0;
      if (k < 500) v = W[cc * 500 + k];
      else if (k == 511) v = bb[cc];
    }
  }
  dst[idx] = f2bf(v);
}

// ---------------------------------------------------------------------------
// Planar-flow parameter precompute: per layer l -> [w0,w1,w2,b,uh0,uh1,uh2,uw]
// ---------------------------------------------------------------------------
__global__ void flow_prep(const float* __restrict__ fw, const float* __restrict__ fb,
                          const float* __restrict__ fu, float* __restrict__ fp)
{
  int l = threadIdx.x;
  if (l >= 20) return;
  float w0 = fw[l*3+0], w1 = fw[l*3+1], w2 = fw[l*3+2];
  float u0 = fu[l*3+0], u1 = fu[l*3+1], u2 = fu[l*3+2];
  float wu = w0*u0 + w1*u1 + w2*u2;
  float m  = -1.f + fast_softplus(wu);
  float ww = w0*w0 + w1*w1 + w2*w2 + 1e-7f;
  float s  = (m - wu) / ww;
  float uh0 = u0 + s*w0, uh1 = u1 + s*w1, uh2 = u2 + s*w2;
  float uw  = uh0*w0 + uh1*w1 + uh2*w2;
  fp[l*8+0]=w0; fp[l*8+1]=w1; fp[l*8+2]=w2; fp[l*8+3]=fb[l];
  fp[l*8+4]=uh0; fp[l*8+5]=uh1; fp[l*8+6]=uh2; fp[l*8+7]=uw;
}

// ---------------------------------------------------------------------------
// Persistent batch-partitioned GRU. 32 blocks x 512 threads; block owns 16 batches.
// LDS A-tile [16][584]: cols 0..499 h (bf16), 511 = 1.0 (bhh row), 512.. = input
// (enc: 38 x cols + col550=1.0; dec: 3 z cols + col515=1.0).
// frag: [KS][96][64][8] swizzled weights. hout: [B*T][512] bf16, col511=1.0.
// ---------------------------------------------------------------------------
__global__ __launch_bounds__(512, 2) void gru_kernel(
    const u16* __restrict__ frag,
    const float* __restrict__ xsrc,   // enc only: [512][100][38] f32
    const u16* __restrict__ zsrc,     // dec only: [51200][4] bf16 (z0,z1,z2,1.0)
    u16* __restrict__ hout,
    int is_enc)
{
  constexpr int ROWW = 584;
  __shared__ u16 A[16 * ROWW];
  const int tid  = threadIdx.x;
  const int lane = tid & 63;
  const int w    = tid >> 6;
  const int q    = lane >> 4;
  const int c    = lane & 15;
  const int b0   = blockIdx.x * 16;

  for (int i = tid; i < 16 * ROWW; i += 512) A[i] = 0;
  __syncthreads();
  if (tid < 16){
    A[tid * ROWW + 511] = 0x3F80;               // 1.0 -> bhh bias row
    if (is_enc) A[tid * ROWW + 550] = 0x3F80;   // 1.0 -> bih bias row (enc)
  }
  // x-loader static mapping (608 = 16*38 elements over 512 threads, 2 slots)
  const int xr0 = tid / 38, xc0 = tid - (tid / 38) * 38;
  const int t2  = tid + 512;
  const int xr1 = t2 / 38, xc1 = t2 - (t2 / 38) * 38;
  const bool x1ok = (t2 < 608);
  float xv0 = 0.f, xv1 = 0.f;
  u16x4 zv; zv[0]=0; zv[1]=0; zv[2]=0; zv[3]=0;
  if (is_enc){
    xv0 = xsrc[((size_t)(b0 + xr0) * 100 + 0) * 38 + xc0];
    if (x1ok) xv1 = xsrc[((size_t)(b0 + xr1) * 100 + 0) * 38 + xc1];
  } else if (tid < 16){
    zv = *(const u16x4*)(zsrc + ((size_t)(b0 + tid) * 100 + 0) * 4);
  }
  if (is_enc){
    A[xr0 * ROWW + 512 + xc0] = f2bf(xv0);
    if (x1ok) A[xr1 * ROWW + 512 + xc1] = f2bf(xv1);
  } else if (tid < 16){
    *(u16x4*)(A + tid * ROWW + 512) = zv;
  }

  const int kx = is_enc ? 2 : 1;
  const u16* Arow = A + c * ROWW + q * 8;   // A-operand: m=lane&15, k=quad*8+j

  for (int t = 0; t < 100; ++t){
    __syncthreads();   // h_t and input_t staged in A

    f32x4 acc[3][4], accx[4];
    #pragma unroll
    for (int g = 0; g < 3; ++g)
      #pragma unroll
      for (int i = 0; i < 4; ++i) acc[g][i] = zero4();
    #pragma unroll
    for (int i = 0; i < 4; ++i) accx[i] = zero4();

    // hidden-state K-steps (K=512): all gates
    #pragma unroll 1
    for (int ks = 0; ks < 16; ++ks){
      bf16x8 af = __builtin_bit_cast(bf16x8, *(const u16x8*)(Arow + ks * 32));
      #pragma unroll
      for (int g = 0; g < 3; ++g){
        #pragma unroll
        for (int i = 0; i < 4; ++i){
          const int nt = g * 32 + w * 4 + i;
          bf16x8 bf = __builtin_bit_cast(bf16x8,
              *(const u16x8*)(frag + (((size_t)ks * 96 + nt) * 64 + lane) * 8));
          acc[g][i] = MFMA16x16(af, bf, acc[g][i]);
        }
      }
    }
    // input K-steps: r/z gates fold in, n-gate input part kept separate (accx)
    #pragma unroll 1
    for (int k2 = 0; k2 < kx; ++k2){
      const int ks = 16 + k2;
      bf16x8 af = __builtin_bit_cast(bf16x8, *(const u16x8*)(Arow + ks * 32));
      #pragma unroll
      for (int i = 0; i < 4; ++i){
        const int ntb = w * 4 + i;
        bf16x8 br = __builtin_bit_cast(bf16x8,
            *(const u16x8*)(frag + (((size_t)ks * 96 + ntb) * 64 + lane) * 8));
        acc[0][i] = MFMA16x16(af, br, acc[0][i]);
        bf16x8 bz = __builtin_bit_cast(bf16x8,
            *(const u16x8*)(frag + (((size_t)ks * 96 + 32 + ntb) * 64 + lane) * 8));
        acc[1][i] = MFMA16x16(af, bz, acc[1][i]);
        bf16x8 bn = __builtin_bit_cast(bf16x8,
            *(const u16x8*)(frag + (((size_t)ks * 96 + 64 + ntb) * 64 + lane) * 8));
        accx[i] = MFMA16x16(af, bn, accx[i]);
      }
    }

    // gate math in C-layout registers: row=q*4+r, col=lane&15
    u16 hv[4][4];
    #pragma unroll
    for (int i = 0; i < 4; ++i){
      const int jc = (w * 4 + i) * 16 + c;
      #pragma unroll
      for (int r = 0; r < 4; ++r){
        const int row = q * 4 + r;
        float rr = fast_sigmoid(acc[0][i][r]);
        float zg = fast_sigmoid(acc[1][i][r]);
        float nn = fast_tanh(accx[i][r] + rr * acc[2][i][r]);
        float hold = bf2f(A[row * ROWW + jc]);
        float hnew = (1.f - zg) * nn + zg * hold;
        hv[i][r] = (jc < 500) ? f2bf(hnew) : ((jc == 511) ? (u16)0x3F80 : (u16)0);
      }
    }
    // prefetch next input while waiting
    if (t < 99){
      if (is_enc){
        xv0 = xsrc[((size_t)(b0 + xr0) * 100 + (t + 1)) * 38 + xc0];
        if (x1ok) xv1 = xsrc[((size_t)(b0 + xr1) * 100 + (t + 1)) * 38 + xc1];
      } else if (tid < 16){
        zv = *(const u16x4*)(zsrc + ((size_t)(b0 + tid) * 100 + (t + 1)) * 4);
      }
    }
    __syncthreads();   // everyone done reading A
    #pragma unroll
    for (int i = 0; i < 4; ++i){
      const int jc = (w * 4 + i) * 16 + c;
      #pragma unroll
      for (int r = 0; r < 4; ++r){
        const int row = q * 4 + r;
        A[row * ROWW + jc] = hv[i][r];
        hout[((size_t)(b0 + row) * 100 + t) * 512 + jc] = hv[i][r];
      }
    }
    if (t < 99){
      if (is_enc){
        A[xr0 * ROWW + 512 + xc0] = f2bf(xv0);
        if (x1ok) A[xr1 * ROWW + 512 + xc1] = f2bf(xv1);
      } else if (tid < 16){
        *(u16x4*)(A + tid * ROWW + 512) = zv;
      }
    }
  }
}

// ---------------------------------------------------------------------------
// Post-net layer: out[51200][512] = pad( leaky_relu( A[51200][512] @ frag ) ),
// col 511 forced to 1.0 (bias row for the next layer), cols 500..510 -> 0.
// Block = 512 thr: 4 row-blocks x 2 n-halves; wave does [16 rows x 256 cols].
// ---------------------------------------------------------------------------
__global__ __launch_bounds__(512, 2) void gemm512(
    const u16* __restrict__ A, const u16* __restrict__ frag, u16* __restrict__ out)
{
  const int tid = threadIdx.x, lane = tid & 63, w = tid >> 6;
  const int q = lane >> 4, c = lane & 15;
  const int rb = w >> 1, nh = w & 1;
  const size_t rowbase = (size_t)blockIdx.x * 64 + rb * 16;
  f32x4 acc[16];
  #pragma unroll
  for (int i = 0; i < 16; ++i) acc[i] = zero4();
  const u16* Ar = A + (rowbase + c) * 512 + q * 8;
  #pragma unroll 1
  for (int ks = 0; ks < 16; ++ks){
    bf16x8 af = __builtin_bit_cast(bf16x8, *(const u16x8*)(Ar + ks * 32));
    #pragma unroll
    for (int i = 0; i < 16; ++i){
      const int nt = nh * 16 + i;
      bf16x8 bf = __builtin_bit_cast(bf16x8,
          *(const u16x8*)(frag + (((size_t)ks * 32 + nt) * 64 + lane) * 8));
      acc[i] = MFMA16x16(af, bf, acc[i]);
    }
  }
  #pragma unroll
  for (int i = 0; i < 16; ++i){
    const int col = (nh * 16 + i) * 16 + c;
    #pragma unroll
    for (int r = 0; r < 4; ++r){
      const size_t row = rowbase + q * 4 + r;
      float v = acc[i][r];
      v = fmaxf(v, 0.1f * v);   // leaky_relu(0.1)
      u16 o = (col < 500) ? f2bf(v) : ((col == 511) ? (u16)0x3F80 : (u16)0);
      out[row * 512 + col] = o;
    }
  }
}

// ---------------------------------------------------------------------------
// hm precompute: hm[51200][8], cols 0..2 = h@zmW^T+zm_b, 3..5 = h@zsW^T+zs_b
// ---------------------------------------------------------------------------
__global__ __launch_bounds__(512, 2) void hm_kernel(
    const u16* __restrict__ A, const u16* __restrict__ zfrag, float* __restrict__ hm)
{
  const int tid = threadIdx.x, lane = tid & 63, w = tid >> 6;
  const int q = lane >> 4, c = lane & 15;
  const size_t rowbase = (size_t)blockIdx.x * 128 + w * 16;
  f32x4 acc = zero4();
  const u16* Ar = A + (rowbase + c) * 512 + q * 8;
  #pragma unroll 1
  for (int ks = 0; ks < 16; ++ks){
    bf16x8 af = __builtin_bit_cast(bf16x8, *(const u16x8*)(Ar + ks * 32));
    bf16x8 bf = __builtin_bit_cast(bf16x8,
        *(const u16x8*)(zfrag + (((size_t)ks * 64) + lane) * 8));
    acc = MFMA16x16(af, bf, acc);
  }
  if (c < 6){
    #pragma unroll
    for (int r = 0; r < 4; ++r)
      hm[(rowbase + q * 4 + r) * 8 + c] = acc[r];
  }
}

// ---------------------------------------------------------------------------
// Sequential latent scan: only the 3x3 z-feedback part (h-part precomputed).
// ---------------------------------------------------------------------------
__global__ void scan_kernel(const float* __restrict__ hm, const float* __restrict__ eps,
                            const float* __restrict__ zmW, const float* __restrict__ zsW,
                            float* __restrict__ zgen, float* __restrict__ zmu,
                            float* __restrict__ zstd)
{
  int b = blockIdx.x * blockDim.x + threadIdx.x;
  if (b >= 512) return;
  float Wm[3][3], Ws[3][3];
  #pragma unroll
  for (int j = 0; j < 3; ++j)
    #pragma unroll
    for (int k = 0; k < 3; ++k){
      Wm[j][k] = zmW[j * 503 + 500 + k];
      Ws[j][k] = zsW[j * 503 + 500 + k];
    }
  float z0 = 0.f, z1 = 0.f, z2 = 0.f;
  for (int t = 0; t < 100; ++t){
    size_t row = (size_t)b * 100 + t;
    const float* h = hm + row * 8;
    const float* e = eps + row * 3;
    float zn[3];
    #pragma unroll
    for (int j = 0; j < 3; ++j){
      float m_ = h[j]     + Wm[j][0]*z0 + Wm[j][1]*z1 + Wm[j][2]*z2;
      float p_ = h[3 + j] + Ws[j][0]*z0 + Ws[j][1]*z1 + Ws[j][2]*z2;
      float s_ = fast_softplus(p_) + 1e-4f;
      float zv = m_ + s_ * e[j];
      zgen[row * 3 + j] = zv;
      zmu [row * 3 + j] = m_;
      zstd[row * 3 + j] = s_;
      zn[j] = zv;
    }
    z0 = zn[0]; z1 = zn[1]; z2 = zn[2];
  }
}

// ---------------------------------------------------------------------------
// Planar flow (no scan feedback -> parallel over all 51200 (b,t))
// ---------------------------------------------------------------------------
__global__ void flow_kernel(const float* __restrict__ zgen, const float* __restrict__ fp,
                            float* __restrict__ zfin, float* __restrict__ ldj,
                            u16* __restrict__ zf16)
{
  int idx = blockIdx.x * blockDim.x + threadIdx.x;
  if (idx >= 51200) return;
  float z0 = zgen[idx*3+0], z1 = zgen[idx*3+1], z2 = zgen[idx*3+2];
  float ld = 0.f;
  #pragma unroll 1
  for (int l = 0; l < 20; ++l){
    const float* p = fp + l * 8;
    float lin = z0*p[0] + z1*p[1] + z2*p[2] + p[3];
    float tt = fast_tanh(lin);
    z0 += p[4]*tt; z1 += p[5]*tt; z2 += p[6]*tt;
    float det = 1.f + (1.f - tt*tt) * p[7];
    ld += __logf(fabsf(det) + 1e-7f);
  }
  zfin[idx*3+0] = z0; zfin[idx*3+1] = z1; zfin[idx*3+2] = z2;
  ldj[idx] = ld;
  u16x4 o; o[0] = f2bf(z0); o[1] = f2bf(z1); o[2] = f2bf(z2); o[3] = 0x3F80;
  *(u16x4*)(zf16 + (size_t)idx * 4) = o;
}

// ---------------------------------------------------------------------------
// Output heads: x_rec_mu = hd@xmW^T+xm_b ; x_rec_std = softplus(hd@xsW^T+xs_b)+1e-4
// ---------------------------------------------------------------------------
__global__ __launch_bounds__(512, 2) void heads_kernel(
    const u16* __restrict__ A, const u16* __restrict__ hfrag,
    float* __restrict__ out_mu, float* __restrict__ out_std)
{
  const int tid = threadIdx.x, lane = tid & 63, w = tid >> 6;
  const int q = lane >> 4, c = lane & 15;
  const size_t rowbase = (size_t)blockIdx.x * 128 + w * 16;
  f32x4 acc[6];
  #pragma unroll
  for (int i = 0; i < 6; ++i) acc[i] = zero4();
  const u16* Ar = A + (rowbase + c) * 512 + q * 8;
  #pragma unroll 1
  for (int ks = 0; ks < 16; ++ks){
    bf16x8 af = __builtin_bit_cast(bf16x8, *(const u16x8*)(Ar + ks * 32));
    #pragma unroll
    for (int i = 0; i < 6; ++i){
      bf16x8 bf = __builtin_bit_cast(bf16x8,
          *(const u16x8*)(hfrag + (((size_t)ks * 6 + i) * 64 + lane) * 8));
      acc[i] = MFMA16x16(af, bf, acc[i]);
    }
  }
  #pragma unroll
  for (int i = 0; i < 6; ++i){
    const int cc  = i * 16 + c;          // 0..95
    const int grp = cc / 48;
    const int col = cc - grp * 48;
    if (col < 38){
      #pragma unroll
      for (int r = 0; r < 4; ++r){
        const size_t row = rowbase + q * 4 + r;
        float v = acc[i][r];
        if (grp == 0) out_mu[row * 38 + col] = v;
        else          out_std[row * 38 + col] = fast_softplus(v) + 1e-4f;
      }
    }
  }
}

// ---------------------------------------------------------------------------
extern "C" void kernel_launch(void* const* d_in, const int* in_sizes, int n_in,
                              void* d_out, int out_size, void* d_ws, size_t ws_size,
                              hipStream_t stream)
{
  const float* x       = (const float*)d_in[0];
  const float* eps     = (const float*)d_in[1];
  const float* enc_Wih = (const float*)d_in[2];
  const float* enc_Whh = (const float*)d_in[3];
  const float* enc_bih = (const float*)d_in[4];
  const float* enc_bhh = (const float*)d_in[5];
  const float* enc_W1  = (const float*)d_in[6];
  const float* enc_b1  = (const float*)d_in[7];
  const float* enc_W2  = (const float*)d_in[8];
  const float* enc_b2  = (const float*)d_in[9];
  const float* zm_W    = (const float*)d_in[10];
  const float* zm_b    = (const float*)d_in[11];
  const float* zs_W    = (const float*)d_in[12];
  const float* zs_b    = (const float*)d_in[13];
  const float* flow_w  = (const float*)d_in[14];
  const float* flow_b  = (const float*)d_in[15];
  const float* flow_u  = (const float*)d_in[16];
  const float* dec_Wih = (const float*)d_in[17];
  const float* dec_Whh = (const float*)d_in[18];
  const float* dec_bih = (const float*)d_in[19];
  const float* dec_bhh = (const float*)d_in[20];
  const float* dec_W1  = (const float*)d_in[21];
  const float* dec_b1  = (const float*)d_in[22];
  const float* dec_W2  = (const float*)d_in[23];
  const float* dec_b2  = (const float*)d_in[24];
  const float* xm_W    = (const float*)d_in[25];
  const float* xm_b    = (const float*)d_in[26];
  const float* xs_W    = (const float*)d_in[27];
  const float* xs_b    = (const float*)d_in[28];
  (void)in_sizes; (void)n_in; (void)out_size; (void)ws_size;

  float* out    = (float*)d_out;
  float* r_mu   = out;                 // [512,100,38]
  float* r_std  = out + 1945600;       // [512,100,38]
  float* r_zgen = out + 3891200;       // [512,100,3]
  float* r_zfin = out + 4044800;       // [512,100,3]
  float* r_zmu  = out + 4198400;       // [512,100,3]
  float* r_zstd = out + 4352000;       // [512,100,3]
  float* r_ldj  = out + 4505600;       // [512,100,1]

  char* ws = (char*)d_ws;
  size_t off = 0;
  auto alloc = [&](size_t bytes)->char*{
    char* p = ws + off;
    off += (bytes + 255) & ~(size_t)255;
    return p;
  };
  u16* ENCF  = (u16*)alloc((size_t)18*96*512*2);
  u16* DECF  = (u16*)alloc((size_t)17*96*512*2);
  u16* PF0   = (u16*)alloc((size_t)16*32*512*2);
  u16* PF1   = (u16*)alloc((size_t)16*32*512*2);
  u16* PF2   = (u16*)alloc((size_t)16*32*512*2);
  u16* PF3   = (u16*)alloc((size_t)16*32*512*2);
  u16* ZFR   = (u16*)alloc((size_t)16*1*512*2);
  u16* HFR   = (u16*)alloc((size_t)16*6*512*2);
  float* FPP = (float*)alloc((size_t)20*8*4);
  u16* H1    = (u16*)alloc((size_t)51200*512*2);
  u16* P1    = (u16*)alloc((size_t)51200*512*2);
  u16* P2    = (u16*)alloc((size_t)51200*512*2);
  float* HM  = (float*)alloc((size_t)51200*8*4);
  u16* ZF16  = (u16*)alloc((size_t)51200*4*2);

  // --- weight prep (runs every call; ws is re-poisoned by harness) ---
  build_frag<<<(18*96*512+255)/256,256,0,stream>>>(ENCF,0,18,96,enc_Whh,enc_bhh,enc_Wih,enc_bih);
  build_frag<<<(17*96*512+255)/256,256,0,stream>>>(DECF,1,17,96,dec_Whh,dec_bhh,dec_Wih,dec_bih);
  build_frag<<<(16*32*512+255)/256,256,0,stream>>>(PF0,2,16,32,enc_W1,enc_b1,nullptr,nullptr);
  build_frag<<<(16*32*512+255)/256,256,0,stream>>>(PF1,2,16,32,enc_W2,enc_b2,nullptr,nullptr);
  build_frag<<<(16*32*512+255)/256,256,0,stream>>>(PF2,2,16,32,dec_W1,dec_b1,nullptr,nullptr);
  build_frag<<<(16*32*512+255)/256,256,0,stream>>>(PF3,2,16,32,dec_W2,dec_b2,nullptr,nullptr);
  build_frag<<<(16*1*512+255)/256,256,0,stream>>>(ZFR,3,16,1,zm_W,zm_b,zs_W,zs_b);
  build_frag<<<(16*6*512+255)/256,256,0,stream>>>(HFR,4,16,6,xm_W,xm_b,xs_W,xs_b);
  flow_prep<<<1,64,0,stream>>>(flow_w,flow_b,flow_u,FPP);

  // --- encoder ---
  gru_kernel<<<32,512,0,stream>>>(ENCF, x, nullptr, H1, 1);
  gemm512<<<800,512,0,stream>>>(H1, PF0, P1);
  gemm512<<<800,512,0,stream>>>(P1, PF1, P2);
  hm_kernel<<<400,512,0,stream>>>(P2, ZFR, HM);

  // --- latent scan + planar flow ---
  scan_kernel<<<2,256,0,stream>>>(HM, eps, zm_W, zs_W, r_zgen, r_zmu, r_zstd);
  flow_kernel<<<200,256,0,stream>>>(r_zgen, FPP, r_zfin, r_ldj, ZF16);

  // --- decoder ---
  gru_kernel<<<32,512,0,stream>>>(DECF, nullptr, ZF16, H1, 0);
  gemm512<<<800,512,0,stream>>>(H1, PF2, P1);
  gemm512<<<800,512,0,stream>>>(P1, PF3, P2);
  heads_kernel<<<400,512,0,stream>>>(P2, HFR, r_mu, r_std);
}

// Round 2
// 4460.151 us; speedup vs baseline: 1.2151x; 1.2151x over previous
//
#include <hip/hip_runtime.h>

typedef unsigned short u16;
typedef unsigned int u32;
typedef __bf16 bf16x8 __attribute__((ext_vector_type(8)));
typedef float f32x4 __attribute__((ext_vector_type(4)));
typedef u16 u16x8 __attribute__((ext_vector_type(8)));
typedef u16 u16x4 __attribute__((ext_vector_type(4)));

#define MFMA16x16(a,b,c) __builtin_amdgcn_mfma_f32_16x16x32_bf16((a),(b),(c),0,0,0)

static __device__ __forceinline__ u16 f2bf(float f){
  u32 u = __builtin_bit_cast(u32, f);
  u += 0x7fffu + ((u >> 16) & 1u);
  return (u16)(u >> 16);
}
static __device__ __forceinline__ float bf2f(u16 h){
  u32 u = ((u32)h) << 16;
  return __builtin_bit_cast(float, u);
}
static __device__ __forceinline__ float fast_sigmoid(float x){
  return 1.f / (1.f + __expf(-x));
}
static __device__ __forceinline__ float fast_tanh(float x){
  float e = __expf(2.f * x);
  return 1.f - 2.f / (e + 1.f);
}
static __device__ __forceinline__ float fast_softplus(float x){
  return (x > 15.f) ? x : __logf(1.f + __expf(x));
}
static __device__ __forceinline__ f32x4 zero4(){
  f32x4 v; v[0]=0.f; v[1]=0.f; v[2]=0.f; v[3]=0.f; return v;
}

// ---------------------------------------------------------------------------
// Weight swizzle into MFMA B-fragment order:
// dst[ks][nt][lane][j] = W[k = ks*32 + (lane>>4)*8 + j][ncol = nt*16 + (lane&15)]
// modes: 0 GRU hidden (KS=16)  2 post(500x500+b)  3 zW(zm/zs)  4 heads(xm/xs)
//        5 enc gi (Wih [1500][38], KS=2)
// ---------------------------------------------------------------------------
__global__ void build_frag(u16* __restrict__ dst, int mode, int KS, int NT,
                           const float* __restrict__ W0, const float* __restrict__ b0,
                           const float* __restrict__ W1, const float* __restrict__ b1)
{
  int idx = blockIdx.x * 256 + threadIdx.x;
  int total = KS * NT * 512;
  if (idx >= total) return;
  int j    = idx & 7;
  int lane = (idx >> 3) & 63;
  int ntks = idx >> 9;
  int nt   = ntks % NT;
  int ks   = ntks / NT;
  int k    = ks * 32 + ((lane >> 4) << 3) + j;
  int ncol = (nt << 4) + (lane & 15);
  float v = 0.f;
  if (mode == 0){                         // GRU hidden: rows 0..499 Whh^T, 511 bhh
    int g = ncol >> 9;
    int jin = ncol & 511;
    if (jin < 500){
      int row = g * 500 + jin;            // row of Whh [1500][500]
      if (k < 500) v = W0[row * 500 + k];
      else if (k == 511) v = b0[row];
    }
  } else if (mode == 2){                  // post: W0 [500][500], bias row 511
    if (ncol < 500){
      if (k < 500) v = W0[ncol * 500 + k];
      else if (k == 511) v = b0[ncol];
    }
  } else if (mode == 3){                  // zW: cols 0..2 zm (W0 [3][503]), 3..5 zs
    int c = ncol;
    if (c < 3){
      if (k < 500) v = W0[c * 503 + k];
      else if (k == 511) v = b0[c];
    } else if (c < 6){
      int cc = c - 3;
      if (k < 500) v = W1[cc * 503 + k];
      else if (k == 511) v = b1[cc];
    }
  } else if (mode == 4){                  // heads: cols 0..47 xm (valid<38), 48..95 xs
    int grp = ncol / 48;
    int cc  = ncol - grp * 48;
    if (grp < 2 && cc < 38){
      const float* W  = grp ? W1 : W0;
      const float* bb = grp ? b1 : b0;
      if (k < 500) v = W[cc * 500 + k];
      else if (k == 511) v = bb[cc];
    }
  } else {                                // mode 5: enc Wih [1500][38], no bias row
    int g = ncol >> 9;
    int jin = ncol & 511;
    if (jin < 500 && k < 38) v = W0[(g * 500 + jin) * 38 + k];
  }
  dst[idx] = f2bf(v);
}

// ---------------------------------------------------------------------------
// Planar-flow parameter precompute: per layer l -> [w0,w1,w2,b,uh0,uh1,uh2,uw]
// ---------------------------------------------------------------------------
__global__ void flow_prep(const float* __restrict__ fw, const float* __restrict__ fb,
                          const float* __restrict__ fu, float* __restrict__ fp)
{
  int l = threadIdx.x;
  if (l >= 20) return;
  float w0 = fw[l*3+0], w1 = fw[l*3+1], w2 = fw[l*3+2];
  float u0 = fu[l*3+0], u1 = fu[l*3+1], u2 = fu[l*3+2];
  float wu = w0*u0 + w1*u1 + w2*u2;
  float m  = -1.f + fast_softplus(wu);
  float ww = w0*w0 + w1*w1 + w2*w2 + 1e-7f;
  float s  = (m - wu) / ww;
  float uh0 = u0 + s*w0, uh1 = u1 + s*w1, uh2 = u2 + s*w2;
  float uw  = uh0*w0 + uh1*w1 + uh2*w2;
  fp[l*8+0]=w0; fp[l*8+1]=w1; fp[l*8+2]=w2; fp[l*8+3]=fb[l];
  fp[l*8+4]=uh0; fp[l*8+5]=uh1; fp[l*8+6]=uh2; fp[l*8+7]=uw;
}

// ---------------------------------------------------------------------------
// Encoder input-gates precompute: gi[51200][1536] = x[51200][38] @ Wih^T + bih
// (gate col layout g*512 + hcol, padded). Block = 512 thr: 8 waves x 12 nt,
// M = 32 rows (2 row-tiles). K padded to 64 (2 ks).
// ---------------------------------------------------------------------------
__global__ __launch_bounds__(512, 2) void gi_enc_kernel(
    const float* __restrict__ x, const u16* __restrict__ frag2,
    const float* __restrict__ bih, u16* __restrict__ gi)
{
  const int tid = threadIdx.x, lane = tid & 63, v = tid >> 6;
  const int q = lane >> 4, c = lane & 15;
  const size_t rowbase = (size_t)blockIdx.x * 32;
  u16 a[2][2][8];
  #pragma unroll
  for (int tile = 0; tile < 2; ++tile){
    const float* xr = x + (rowbase + tile*16 + c) * 38;
    #pragma unroll
    for (int j = 0; j < 8; ++j){
      int k0 = q*8 + j;
      a[tile][0][j] = f2bf(xr[k0]);                       // k0 <= 31 < 38
      int k1 = 32 + q*8 + j;
      a[tile][1][j] = (k1 < 38) ? f2bf(xr[k1]) : (u16)0;
    }
  }
  f32x4 acc[2][12];
  #pragma unroll
  for (int tile = 0; tile < 2; ++tile)
    #pragma unroll
    for (int i = 0; i < 12; ++i) acc[tile][i] = zero4();
  #pragma unroll
  for (int i = 0; i < 12; ++i){
    const int nt = v*12 + i;
    bf16x8 b0 = __builtin_bit_cast(bf16x8,
        *(const u16x8*)(frag2 + (((size_t)0*96 + nt)*64 + lane)*8));
    bf16x8 b1 = __builtin_bit_cast(bf16x8,
        *(const u16x8*)(frag2 + (((size_t)1*96 + nt)*64 + lane)*8));
    #pragma unroll
    for (int tile = 0; tile < 2; ++tile){
      bf16x8 a0 = __builtin_bit_cast(bf16x8, *(const u16x8*)a[tile][0]);
      bf16x8 a1 = __builtin_bit_cast(bf16x8, *(const u16x8*)a[tile][1]);
      acc[tile][i] = MFMA16x16(a0, b0, acc[tile][i]);
      acc[tile][i] = MFMA16x16(a1, b1, acc[tile][i]);
    }
  }
  #pragma unroll
  for (int i = 0; i < 12; ++i){
    const int nt = v*12 + i;
    const int ncol = nt*16 + c;
    const int g = ncol >> 9, jin = ncol & 511;
    const float bias = (jin < 500) ? bih[g*500 + jin] : 0.f;
    #pragma unroll
    for (int tile = 0; tile < 2; ++tile)
      #pragma unroll
      for (int r = 0; r < 4; ++r){
        size_t row = rowbase + tile*16 + q*4 + r;
        gi[row*1536 + ncol] = f2bf(acc[tile][i][r] + bias);
      }
  }
}

// ---------------------------------------------------------------------------
// Decoder input-gates precompute (K=3, VALU): gi = z_fin @ Wih^T + bih
// ---------------------------------------------------------------------------
__global__ void gi_dec_kernel(const float* __restrict__ z, const float* __restrict__ W,
                              const float* __restrict__ b, u16* __restrict__ gi)
{
  int idx = blockIdx.x * 256 + threadIdx.x;
  if (idx >= 51200*192) return;
  int row = idx / 192;
  int c8 = (idx - row*192) * 8;
  float z0 = z[row*3+0], z1 = z[row*3+1], z2 = z[row*3+2];
  u16x8 o;
  #pragma unroll
  for (int j = 0; j < 8; ++j){
    int ncol = c8 + j;
    int g = ncol >> 9, jin = ncol & 511;
    float val = 0.f;
    if (jin < 500){
      int wr = g*500 + jin;
      val = z0*W[wr*3+0] + z1*W[wr*3+1] + z2*W[wr*3+2] + b[wr];
    }
    o[j] = f2bf(val);
  }
  *(u16x8*)(gi + (size_t)row*1536 + c8) = o;
}

// ---------------------------------------------------------------------------
// Register-resident cooperative GRU. Grid 256 = 32 batch-groups x 8 col-slices.
// Block 512 thr = 8 waves = 4 nt-groups x 2 K-halves. Weights live in VGPRs
// for all 100 steps. Per-group h double-buffer in global; per-group counter
// sync (release add / acquire spin, agent scope) between steps.
// group = blockIdx%32 (keeps siblings on one XCD if xcd = blockIdx%8).
// 84 KB LDS forces 1 block/CU -> all 256 blocks co-resident.
// ---------------------------------------------------------------------------
__global__ __launch_bounds__(512, 2) void gru2_kernel(
    const u16* __restrict__ frag, const u16* __restrict__ gi,
    u16* __restrict__ hbuf, u16* __restrict__ hout, u32* __restrict__ cntbase)
{
  __shared__ f32x4 red[5376];               // 86016 B: 12 KB used, rest forces 1 block/CU
  const int tid  = threadIdx.x, lane = tid & 63;
  const int wv   = tid >> 6, igrp = wv & 3, half = wv >> 2;
  const int q    = lane >> 4, c = lane & 15;
  const int gid  = blockIdx.x & 31, s = blockIdx.x >> 5;
  const int b0   = gid * 16;
  const int col  = (s*4 + igrp)*16 + c;
  u32* cnt = cntbase + gid;
  u16* hb  = hbuf + (size_t)gid * 16384;    // two buffers of 16x512

  // --- weights into VGPRs (held for all steps) ---
  u16x8 wf[3][8];
  #pragma unroll
  for (int kk = 0; kk < 8; ++kk){
    const int ks = half*8 + kk;
    #pragma unroll
    for (int g = 0; g < 3; ++g){
      const int nt = g*32 + s*4 + igrp;
      wf[g][kk] = *(const u16x8*)(frag + (((size_t)ks*96 + nt)*64 + lane)*8);
    }
  }
  // --- h0 = 0 (+ col511 = 1.0 bias row) ---
  float hold[4] = {0.f, 0.f, 0.f, 0.f};
  if (half == 0){
    const u16 iv = (col == 511) ? (u16)0x3F80 : (u16)0;
    #pragma unroll
    for (int r = 0; r < 4; ++r) hb[(q*4+r)*512 + col] = iv;
  }
  // --- prefetch gi for t=0 ---
  u16 giv[3][4];
  if (half == 0){
    #pragma unroll
    for (int g = 0; g < 3; ++g)
      #pragma unroll
      for (int r = 0; r < 4; ++r)
        giv[g][r] = __builtin_nontemporal_load(
            gi + ((size_t)(b0 + q*4 + r)*100 + 0)*1536 + g*512 + col);
  }
  __syncthreads();
  if (tid == 0)
    __hip_atomic_fetch_add(cnt, 1u, __ATOMIC_RELEASE, __HIP_MEMORY_SCOPE_AGENT);

  #pragma unroll 1
  for (int t = 0; t < 100; ++t){
    if (tid == 0){
      const u32 target = 8u*(u32)(t+1);
      long guard = 0;
      while (__hip_atomic_load(cnt, __ATOMIC_RELAXED, __HIP_MEMORY_SCOPE_AGENT) < target){
        __builtin_amdgcn_s_sleep(2);
        if (++guard > (1L<<27)) break;     // hang-breaker (produces wrong data, not a hang)
      }
      (void)__hip_atomic_load(cnt, __ATOMIC_ACQUIRE, __HIP_MEMORY_SCOPE_AGENT);
    }
    __syncthreads();
    const u16* cur = hb + (t & 1)*8192;
    u16*       nxt = hb + ((t+1) & 1)*8192;

    f32x4 acc0 = zero4(), acc1 = zero4(), acc2 = zero4();
    #pragma unroll
    for (int kk = 0; kk < 8; ++kk){
      const int ks = half*8 + kk;
      bf16x8 af = __builtin_bit_cast(bf16x8,
          *(const u16x8*)(cur + c*512 + ks*32 + q*8));
      acc0 = MFMA16x16(af, __builtin_bit_cast(bf16x8, wf[0][kk]), acc0);
      acc1 = MFMA16x16(af, __builtin_bit_cast(bf16x8, wf[1][kk]), acc1);
      acc2 = MFMA16x16(af, __builtin_bit_cast(bf16x8, wf[2][kk]), acc2);
    }
    if (half == 1){
      red[(igrp*3 + 0)*64 + lane] = acc0;
      red[(igrp*3 + 1)*64 + lane] = acc1;
      red[(igrp*3 + 2)*64 + lane] = acc2;
    }
    __syncthreads();
    if (half == 0){
      const f32x4 p0 = red[(igrp*3+0)*64 + lane];
      const f32x4 p1 = red[(igrp*3+1)*64 + lane];
      const f32x4 p2 = red[(igrp*3+2)*64 + lane];
      #pragma unroll
      for (int r = 0; r < 4; ++r){
        float ar = acc0[r] + p0[r] + bf2f(giv[0][r]);
        float az = acc1[r] + p1[r] + bf2f(giv[1][r]);
        float an = acc2[r] + p2[r];
        float rr = fast_sigmoid(ar);
        float zz = fast_sigmoid(az);
        float nn = fast_tanh(bf2f(giv[2][r]) + rr*an);
        float h  = (1.f - zz)*nn + zz*hold[r];
        hold[r] = h;
        u16 hv16 = (col < 500) ? f2bf(h) : ((col == 511) ? (u16)0x3F80 : (u16)0);
        nxt[(q*4+r)*512 + col] = hv16;
        __builtin_nontemporal_store(hv16,
            hout + ((size_t)(b0 + q*4 + r)*100 + t)*512 + col);
      }
      if (t < 99){
        #pragma unroll
        for (int g = 0; g < 3; ++g)
          #pragma unroll
          for (int r = 0; r < 4; ++r)
            giv[g][r] = __builtin_nontemporal_load(
                gi + ((size_t)(b0 + q*4 + r)*100 + (t+1))*1536 + g*512 + col);
      }
    }
    __syncthreads();
    if (tid == 0)
      __hip_atomic_fetch_add(cnt, 1u, __ATOMIC_RELEASE, __HIP_MEMORY_SCOPE_AGENT);
  }
}

// ---------------------------------------------------------------------------
// Post-net layer: out[51200][512] = pad( leaky_relu( A[51200][512] @ frag ) )
// ---------------------------------------------------------------------------
__global__ __launch_bounds__(512, 2) void gemm512(
    const u16* __restrict__ A, const u16* __restrict__ frag, u16* __restrict__ out)
{
  const int tid = threadIdx.x, lane = tid & 63, w = tid >> 6;
  const int q = lane >> 4, c = lane & 15;
  const int rb = w >> 1, nh = w & 1;
  const size_t rowbase = (size_t)blockIdx.x * 64 + rb * 16;
  f32x4 acc[16];
  #pragma unroll
  for (int i = 0; i < 16; ++i) acc[i] = zero4();
  const u16* Ar = A + (rowbase + c) * 512 + q * 8;
  #pragma unroll 1
  for (int ks = 0; ks < 16; ++ks){
    bf16x8 af = __builtin_bit_cast(bf16x8, *(const u16x8*)(Ar + ks * 32));
    #pragma unroll
    for (int i = 0; i < 16; ++i){
      const int nt = nh * 16 + i;
      bf16x8 bf = __builtin_bit_cast(bf16x8,
          *(const u16x8*)(frag + (((size_t)ks * 32 + nt) * 64 + lane) * 8));
      acc[i] = MFMA16x16(af, bf, acc[i]);
    }
  }
  #pragma unroll
  for (int i = 0; i < 16; ++i){
    const int col = (nh * 16 + i) * 16 + c;
    #pragma unroll
    for (int r = 0; r < 4; ++r){
      const size_t row = rowbase + q * 4 + r;
      float v = acc[i][r];
      v = fmaxf(v, 0.1f * v);
      u16 o = (col < 500) ? f2bf(v) : ((col == 511) ? (u16)0x3F80 : (u16)0);
      out[row * 512 + col] = o;
    }
  }
}

// ---------------------------------------------------------------------------
// hm precompute: hm[51200][8], cols 0..2 = h@zmW^T+zm_b, 3..5 = h@zsW^T+zs_b
// ---------------------------------------------------------------------------
__global__ __launch_bounds__(512, 2) void hm_kernel(
    const u16* __restrict__ A, const u16* __restrict__ zfrag, float* __restrict__ hm)
{
  const int tid = threadIdx.x, lane = tid & 63, w = tid >> 6;
  const int q = lane >> 4, c = lane & 15;
  const size_t rowbase = (size_t)blockIdx.x * 128 + w * 16;
  f32x4 acc = zero4();
  const u16* Ar = A + (rowbase + c) * 512 + q * 8;
  #pragma unroll 1
  for (int ks = 0; ks < 16; ++ks){
    bf16x8 af = __builtin_bit_cast(bf16x8, *(const u16x8*)(Ar + ks * 32));
    bf16x8 bf = __builtin_bit_cast(bf16x8,
        *(const u16x8*)(zfrag + (((size_t)ks * 64) + lane) * 8));
    acc = MFMA16x16(af, bf, acc);
  }
  if (c < 6){
    #pragma unroll
    for (int r = 0; r < 4; ++r)
      hm[(rowbase + q * 4 + r) * 8 + c] = acc[r];
  }
}

// ---------------------------------------------------------------------------
// Sequential latent scan: only the 3x3 z-feedback part (h-part precomputed).
// ---------------------------------------------------------------------------
__global__ void scan_kernel(const float* __restrict__ hm, const float* __restrict__ eps,
                            const float* __restrict__ zmW, const float* __restrict__ zsW,
                            float* __restrict__ zgen, float* __restrict__ zmu,
                            float* __restrict__ zstd)
{
  int b = blockIdx.x * blockDim.x + threadIdx.x;
  if (b >= 512) return;
  float Wm[3][3], Ws[3][3];
  #pragma unroll
  for (int j = 0; j < 3; ++j)
    #pragma unroll
    for (int k = 0; k < 3; ++k){
      Wm[j][k] = zmW[j * 503 + 500 + k];
      Ws[j][k] = zsW[j * 503 + 500 + k];
    }
  float z0 = 0.f, z1 = 0.f, z2 = 0.f;
  for (int t = 0; t < 100; ++t){
    size_t row = (size_t)b * 100 + t;
    const float* h = hm + row * 8;
    const float* e = eps + row * 3;
    float zn[3];
    #pragma unroll
    for (int j = 0; j < 3; ++j){
      float m_ = h[j]     + Wm[j][0]*z0 + Wm[j][1]*z1 + Wm[j][2]*z2;
      float p_ = h[3 + j] + Ws[j][0]*z0 + Ws[j][1]*z1 + Ws[j][2]*z2;
      float s_ = fast_softplus(p_) + 1e-4f;
      float zv = m_ + s_ * e[j];
      zgen[row * 3 + j] = zv;
      zmu [row * 3 + j] = m_;
      zstd[row * 3 + j] = s_;
      zn[j] = zv;
    }
    z0 = zn[0]; z1 = zn[1]; z2 = zn[2];
  }
}

// ---------------------------------------------------------------------------
// Planar flow (no scan feedback -> parallel over all 51200 (b,t))
// ---------------------------------------------------------------------------
__global__ void flow_kernel(const float* __restrict__ zgen, const float* __restrict__ fp,
                            float* __restrict__ zfin, float* __restrict__ ldj)
{
  int idx = blockIdx.x * blockDim.x + threadIdx.x;
  if (idx >= 51200) return;
  float z0 = zgen[idx*3+0], z1 = zgen[idx*3+1], z2 = zgen[idx*3+2];
  float ld = 0.f;
  #pragma unroll 1
  for (int l = 0; l < 20; ++l){
    const float* p = fp + l * 8;
    float lin = z0*p[0] + z1*p[1] + z2*p[2] + p[3];
    float tt = fast_tanh(lin);
    z0 += p[4]*tt; z1 += p[5]*tt; z2 += p[6]*tt;
    float det = 1.f + (1.f - tt*tt) * p[7];
    ld += __logf(fabsf(det) + 1e-7f);
  }
  zfin[idx*3+0] = z0; zfin[idx*3+1] = z1; zfin[idx*3+2] = z2;
  ldj[idx] = ld;
}

// ---------------------------------------------------------------------------
// Output heads: x_rec_mu = hd@xmW^T+xm_b ; x_rec_std = softplus(hd@xsW^T+xs_b)+1e-4
// ---------------------------------------------------------------------------
__global__ __launch_bounds__(512, 2) void heads_kernel(
    const u16* __restrict__ A, const u16* __restrict__ hfrag,
    float* __restrict__ out_mu, float* __restrict__ out_std)
{
  const int tid = threadIdx.x, lane = tid & 63, w = tid >> 6;
  const int q = lane >> 4, c = lane & 15;
  const size_t rowbase = (size_t)blockIdx.x * 128 + w * 16;
  f32x4 acc[6];
  #pragma unroll
  for (int i = 0; i < 6; ++i) acc[i] = zero4();
  const u16* Ar = A + (rowbase + c) * 512 + q * 8;
  #pragma unroll 1
  for (int ks = 0; ks < 16; ++ks){
    bf16x8 af = __builtin_bit_cast(bf16x8, *(const u16x8*)(Ar + ks * 32));
    #pragma unroll
    for (int i = 0; i < 6; ++i){
      bf16x8 bf = __builtin_bit_cast(bf16x8,
          *(const u16x8*)(hfrag + (((size_t)ks * 6 + i) * 64 + lane) * 8));
      acc[i] = MFMA16x16(af, bf, acc[i]);
    }
  }
  #pragma unroll
  for (int i = 0; i < 6; ++i){
    const int cc  = i * 16 + c;
    const int grp = cc / 48;
    const int col = cc - grp * 48;
    if (col < 38){
      #pragma unroll
      for (int r = 0; r < 4; ++r){
        const size_t row = rowbase + q * 4 + r;
        float v = acc[i][r];
        if (grp == 0) out_mu[row * 38 + col] = v;
        else          out_std[row * 38 + col] = fast_softplus(v) + 1e-4f;
      }
    }
  }
}

// ---------------------------------------------------------------------------
extern "C" void kernel_launch(void* const* d_in, const int* in_sizes, int n_in,
                              void* d_out, int out_size, void* d_ws, size_t ws_size,
                              hipStream_t stream)
{
  const float* x       = (const float*)d_in[0];
  const float* eps     = (const float*)d_in[1];
  const float* enc_Wih = (const float*)d_in[2];
  const float* enc_Whh = (const float*)d_in[3];
  const float* enc_bih = (const float*)d_in[4];
  const float* enc_bhh = (const float*)d_in[5];
  const float* enc_W1  = (const float*)d_in[6];
  const float* enc_b1  = (const float*)d_in[7];
  const float* enc_W2  = (const float*)d_in[8];
  const float* enc_b2  = (const float*)d_in[9];
  const float* zm_W    = (const float*)d_in[10];
  const float* zm_b    = (const float*)d_in[11];
  const float* zs_W    = (const float*)d_in[12];
  const float* zs_b    = (const float*)d_in[13];
  const float* flow_w  = (const float*)d_in[14];
  const float* flow_b  = (const float*)d_in[15];
  const float* flow_u  = (const float*)d_in[16];
  const float* dec_Wih = (const float*)d_in[17];
  const float* dec_Whh = (const float*)d_in[18];
  const float* dec_bih = (const float*)d_in[19];
  const float* dec_bhh = (const float*)d_in[20];
  const float* dec_W1  = (const float*)d_in[21];
  const float* dec_b1  = (const float*)d_in[22];
  const float* dec_W2  = (const float*)d_in[23];
  const float* dec_b2  = (const float*)d_in[24];
  const float* xm_W    = (const float*)d_in[25];
  const float* xm_b    = (const float*)d_in[26];
  const float* xs_W    = (const float*)d_in[27];
  const float* xs_b    = (const float*)d_in[28];
  (void)in_sizes; (void)n_in; (void)out_size; (void)ws_size;

  float* out    = (float*)d_out;
  float* r_mu   = out;                 // [512,100,38]
  float* r_std  = out + 1945600;       // [512,100,38]
  float* r_zgen = out + 3891200;       // [512,100,3]
  float* r_zfin = out + 4044800;       // [512,100,3]
  float* r_zmu  = out + 4198400;       // [512,100,3]
  float* r_zstd = out + 4352000;       // [512,100,3]
  float* r_ldj  = out + 4505600;       // [512,100,1]

  char* ws = (char*)d_ws;
  size_t off = 0;
  auto alloc = [&](size_t bytes)->char*{
    char* p = ws + off;
    off += (bytes + 255) & ~(size_t)255;
    return p;
  };
  u16* H1    = (u16*)alloc((size_t)51200*512*2);     // GRU hidden states
  u16* BIG   = (u16*)alloc((size_t)51200*1536*2);    // gi buffer; aliased as P1/P2
  u16* P1    = BIG;                                  // [51200][512]
  u16* P2    = BIG + (size_t)51200*512;              // [51200][512]
  u16* ENCF  = (u16*)alloc((size_t)16*96*512*2);
  u16* DECF  = (u16*)alloc((size_t)16*96*512*2);
  u16* EGIF  = (u16*)alloc((size_t)2*96*512*2);
  u16* PF0   = (u16*)alloc((size_t)16*32*512*2);
  u16* PF1   = (u16*)alloc((size_t)16*32*512*2);
  u16* PF2   = (u16*)alloc((size_t)16*32*512*2);
  u16* PF3   = (u16*)alloc((size_t)16*32*512*2);
  u16* ZFR   = (u16*)alloc((size_t)16*1*512*2);
  u16* HFR   = (u16*)alloc((size_t)16*6*512*2);
  float* FPP = (float*)alloc((size_t)20*8*4);
  float* HM  = (float*)alloc((size_t)51200*8*4);
  u16* HBUF  = (u16*)alloc((size_t)32*2*16*512*2);
  u32* CNT   = (u32*)alloc(256);

  // --- sync counters + weight prep ---
  hipMemsetAsync(CNT, 0, 256, stream);
  build_frag<<<3072,256,0,stream>>>(ENCF,0,16,96,enc_Whh,enc_bhh,nullptr,nullptr);
  build_frag<<<3072,256,0,stream>>>(DECF,0,16,96,dec_Whh,dec_bhh,nullptr,nullptr);
  build_frag<<<384,256,0,stream>>>(EGIF,5,2,96,enc_Wih,nullptr,nullptr,nullptr);
  build_frag<<<1024,256,0,stream>>>(PF0,2,16,32,enc_W1,enc_b1,nullptr,nullptr);
  build_frag<<<1024,256,0,stream>>>(PF1,2,16,32,enc_W2,enc_b2,nullptr,nullptr);
  build_frag<<<1024,256,0,stream>>>(PF2,2,16,32,dec_W1,dec_b1,nullptr,nullptr);
  build_frag<<<1024,256,0,stream>>>(PF3,2,16,32,dec_W2,dec_b2,nullptr,nullptr);
  build_frag<<<32,256,0,stream>>>(ZFR,3,16,1,zm_W,zm_b,zs_W,zs_b);
  build_frag<<<192,256,0,stream>>>(HFR,4,16,6,xm_W,xm_b,xs_W,xs_b);
  flow_prep<<<1,64,0,stream>>>(flow_w,flow_b,flow_u,FPP);

  // --- encoder ---
  gi_enc_kernel<<<1600,512,0,stream>>>(x, EGIF, enc_bih, BIG);
  gru2_kernel<<<256,512,0,stream>>>(ENCF, BIG, HBUF, H1, CNT);
  gemm512<<<800,512,0,stream>>>(H1, PF0, P1);          // gi dead; BIG reused as P1/P2
  gemm512<<<800,512,0,stream>>>(P1, PF1, P2);
  hm_kernel<<<400,512,0,stream>>>(P2, ZFR, HM);

  // --- latent scan + planar flow ---
  scan_kernel<<<2,256,0,stream>>>(HM, eps, zm_W, zs_W, r_zgen, r_zmu, r_zstd);
  flow_kernel<<<200,256,0,stream>>>(r_zgen, FPP, r_zfin, r_ldj);

  // --- decoder ---
  gi_dec_kernel<<<38400,256,0,stream>>>(r_zfin, dec_Wih, dec_bih, BIG);  // P1/P2 dead
  gru2_kernel<<<256,512,0,stream>>>(DECF, BIG, HBUF, H1, CNT + 32);
  gemm512<<<800,512,0,stream>>>(H1, PF2, P1);          // gi dead again
  gemm512<<<800,512,0,stream>>>(P1, PF3, P2);
  heads_kernel<<<400,512,0,stream>>>(P2, HFR, r_mu, r_std);
}

// Round 3
// 1975.315 us; speedup vs baseline: 2.7437x; 2.2579x over previous
//
#include <hip/hip_runtime.h>

typedef unsigned short u16;
typedef unsigned int u32;
typedef unsigned long long u64;
typedef __bf16 bf16x8 __attribute__((ext_vector_type(8)));
typedef float f32x4 __attribute__((ext_vector_type(4)));
typedef u16 u16x8 __attribute__((ext_vector_type(8)));
typedef u16 u16x4 __attribute__((ext_vector_type(4)));

struct u64pair { u64 a, b; };

#define MFMA16x16(a,b,c) __builtin_amdgcn_mfma_f32_16x16x32_bf16((a),(b),(c),0,0,0)

static __device__ __forceinline__ u16 f2bf(float f){
  u32 u = __builtin_bit_cast(u32, f);
  u += 0x7fffu + ((u >> 16) & 1u);
  return (u16)(u >> 16);
}
static __device__ __forceinline__ float bf2f(u16 h){
  u32 u = ((u32)h) << 16;
  return __builtin_bit_cast(float, u);
}
static __device__ __forceinline__ float fast_sigmoid(float x){
  return 1.f / (1.f + __expf(-x));
}
static __device__ __forceinline__ float fast_tanh(float x){
  float e = __expf(2.f * x);
  return 1.f - 2.f / (e + 1.f);
}
static __device__ __forceinline__ float fast_softplus(float x){
  return (x > 15.f) ? x : __logf(1.f + __expf(x));
}
static __device__ __forceinline__ f32x4 zero4(){
  f32x4 v; v[0]=0.f; v[1]=0.f; v[2]=0.f; v[3]=0.f; return v;
}

// ---------------------------------------------------------------------------
// Weight swizzle into MFMA B-fragment order:
// dst[ks][nt][lane][j] = W[k = ks*32 + (lane>>4)*8 + j][ncol = nt*16 + (lane&15)]
// modes: 0 GRU hidden (KS=16)  2 post(500x500+b)  3 zW(zm/zs)  4 heads(xm/xs)
//        5 enc gi (Wih [1500][38], KS=2)
// ---------------------------------------------------------------------------
__global__ void build_frag(u16* __restrict__ dst, int mode, int KS, int NT,
                           const float* __restrict__ W0, const float* __restrict__ b0,
                           const float* __restrict__ W1, const float* __restrict__ b1)
{
  int idx = blockIdx.x * 256 + threadIdx.x;
  int total = KS * NT * 512;
  if (idx >= total) return;
  int j    = idx & 7;
  int lane = (idx >> 3) & 63;
  int ntks = idx >> 9;
  int nt   = ntks % NT;
  int ks   = ntks / NT;
  int k    = ks * 32 + ((lane >> 4) << 3) + j;
  int ncol = (nt << 4) + (lane & 15);
  float v = 0.f;
  if (mode == 0){                         // GRU hidden: rows 0..499 Whh^T, 511 bhh
    int g = ncol >> 9;
    int jin = ncol & 511;
    if (jin < 500){
      int row = g * 500 + jin;            // row of Whh [1500][500]
      if (k < 500) v = W0[row * 500 + k];
      else if (k == 511) v = b0[row];
    }
  } else if (mode == 2){                  // post: W0 [500][500], bias row 511
    if (ncol < 500){
      if (k < 500) v = W0[ncol * 500 + k];
      else if (k == 511) v = b0[ncol];
    }
  } else if (mode == 3){                  // zW: cols 0..2 zm (W0 [3][503]), 3..5 zs
    int c = ncol;
    if (c < 3){
      if (k < 500) v = W0[c * 503 + k];
      else if (k == 511) v = b0[c];
    } else if (c < 6){
      int cc = c - 3;
      if (k < 500) v = W1[cc * 503 + k];
      else if (k == 511) v = b1[cc];
    }
  } else if (mode == 4){                  // heads: cols 0..47 xm (valid<38), 48..95 xs
    int grp = ncol / 48;
    int cc  = ncol - grp * 48;
    if (grp < 2 && cc < 38){
      const float* W  = grp ? W1 : W0;
      const float* bb = grp ? b1 : b0;
      if (k < 500) v = W[cc * 500 + k];
      else if (k == 511) v = bb[cc];
    }
  } else {                                // mode 5: enc Wih [1500][38], no bias row
    int g = ncol >> 9;
    int jin = ncol & 511;
    if (jin < 500 && k < 38) v = W0[(g * 500 + jin) * 38 + k];
  }
  dst[idx] = f2bf(v);
}

// ---------------------------------------------------------------------------
// Planar-flow parameter precompute: per layer l -> [w0,w1,w2,b,uh0,uh1,uh2,uw]
// ---------------------------------------------------------------------------
__global__ void flow_prep(const float* __restrict__ fw, const float* __restrict__ fb,
                          const float* __restrict__ fu, float* __restrict__ fp)
{
  int l = threadIdx.x;
  if (l >= 20) return;
  float w0 = fw[l*3+0], w1 = fw[l*3+1], w2 = fw[l*3+2];
  float u0 = fu[l*3+0], u1 = fu[l*3+1], u2 = fu[l*3+2];
  float wu = w0*u0 + w1*u1 + w2*u2;
  float m  = -1.f + fast_softplus(wu);
  float ww = w0*w0 + w1*w1 + w2*w2 + 1e-7f;
  float s  = (m - wu) / ww;
  float uh0 = u0 + s*w0, uh1 = u1 + s*w1, uh2 = u2 + s*w2;
  float uw  = uh0*w0 + uh1*w1 + uh2*w2;
  fp[l*8+0]=w0; fp[l*8+1]=w1; fp[l*8+2]=w2; fp[l*8+3]=fb[l];
  fp[l*8+4]=uh0; fp[l*8+5]=uh1; fp[l*8+6]=uh2; fp[l*8+7]=uw;
}

// ---------------------------------------------------------------------------
// Encoder input-gates precompute: gi[51200][1536] = x[51200][38] @ Wih^T + bih
// ---------------------------------------------------------------------------
__global__ __launch_bounds__(512, 2) void gi_enc_kernel(
    const float* __restrict__ x, const u16* __restrict__ frag2,
    const float* __restrict__ bih, u16* __restrict__ gi)
{
  const int tid = threadIdx.x, lane = tid & 63, v = tid >> 6;
  const int q = lane >> 4, c = lane & 15;
  const size_t rowbase = (size_t)blockIdx.x * 32;
  u16 a[2][2][8];
  #pragma unroll
  for (int tile = 0; tile < 2; ++tile){
    const float* xr = x + (rowbase + tile*16 + c) * 38;
    #pragma unroll
    for (int j = 0; j < 8; ++j){
      int k0 = q*8 + j;
      a[tile][0][j] = f2bf(xr[k0]);                       // k0 <= 31 < 38
      int k1 = 32 + q*8 + j;
      a[tile][1][j] = (k1 < 38) ? f2bf(xr[k1]) : (u16)0;
    }
  }
  f32x4 acc[2][12];
  #pragma unroll
  for (int tile = 0; tile < 2; ++tile)
    #pragma unroll
    for (int i = 0; i < 12; ++i) acc[tile][i] = zero4();
  #pragma unroll
  for (int i = 0; i < 12; ++i){
    const int nt = v*12 + i;
    bf16x8 b0 = __builtin_bit_cast(bf16x8,
        *(const u16x8*)(frag2 + (((size_t)0*96 + nt)*64 + lane)*8));
    bf16x8 b1 = __builtin_bit_cast(bf16x8,
        *(const u16x8*)(frag2 + (((size_t)1*96 + nt)*64 + lane)*8));
    #pragma unroll
    for (int tile = 0; tile < 2; ++tile){
      bf16x8 a0 = __builtin_bit_cast(bf16x8, *(const u16x8*)a[tile][0]);
      bf16x8 a1 = __builtin_bit_cast(bf16x8, *(const u16x8*)a[tile][1]);
      acc[tile][i] = MFMA16x16(a0, b0, acc[tile][i]);
      acc[tile][i] = MFMA16x16(a1, b1, acc[tile][i]);
    }
  }
  #pragma unroll
  for (int i = 0; i < 12; ++i){
    const int nt = v*12 + i;
    const int ncol = nt*16 + c;
    const int g = ncol >> 9, jin = ncol & 511;
    const float bias = (jin < 500) ? bih[g*500 + jin] : 0.f;
    #pragma unroll
    for (int tile = 0; tile < 2; ++tile)
      #pragma unroll
      for (int r = 0; r < 4; ++r){
        size_t row = rowbase + tile*16 + q*4 + r;
        gi[row*1536 + ncol] = f2bf(acc[tile][i][r] + bias);
      }
  }
}

// ---------------------------------------------------------------------------
// Decoder input-gates precompute (K=3, VALU): gi = z_fin @ Wih^T + bih
// ---------------------------------------------------------------------------
__global__ void gi_dec_kernel(const float* __restrict__ z, const float* __restrict__ W,
                              const float* __restrict__ b, u16* __restrict__ gi)
{
  int idx = blockIdx.x * 256 + threadIdx.x;
  if (idx >= 51200*192) return;
  int row = idx / 192;
  int c8 = (idx - row*192) * 8;
  float z0 = z[row*3+0], z1 = z[row*3+1], z2 = z[row*3+2];
  u16x8 o;
  #pragma unroll
  for (int j = 0; j < 8; ++j){
    int ncol = c8 + j;
    int g = ncol >> 9, jin = ncol & 511;
    float val = 0.f;
    if (jin < 500){
      int wr = g*500 + jin;
      val = z0*W[wr*3+0] + z1*W[wr*3+1] + z2*W[wr*3+2] + b[wr];
    }
    o[j] = f2bf(val);
  }
  *(u16x8*)(gi + (size_t)row*1536 + c8) = o;
}

// ---------------------------------------------------------------------------
// Register-resident cooperative GRU. Grid 256 = 32 batch-groups x 8 col-slices.
// Weights live in VGPRs for all 100 steps. h exchange goes through Infinity
// Cache via RELAXED agent-scope atomics (sc1 accesses bypass the non-coherent
// per-XCD L2) -- NO wbl2/buffer_inv (the R2 killer: ~40k cyc/step L2 tag
// walks from RELEASE/ACQUIRE). Data->flag ordering: __syncthreads() drains
// vmcnt(0); sc1 store ack = visible at IF. Counters padded to 512 B/group.
// 84 KB LDS forces 1 block/CU -> all 256 blocks co-resident.
// ---------------------------------------------------------------------------
__global__ __launch_bounds__(512, 2) void gru2_kernel(
    const u16* __restrict__ frag, const u16* __restrict__ gi,
    u32* __restrict__ hbufbase, u16* __restrict__ hout, u32* __restrict__ cntbase)
{
  __shared__ f32x4 red[5376];               // 86016 B: 12 KB used, rest forces 1 block/CU
  const int tid  = threadIdx.x, lane = tid & 63;
  const int wv   = tid >> 6, igrp = wv & 3, half = wv >> 2;
  const int q    = lane >> 4, c = lane & 15;
  const int gid  = blockIdx.x & 31, s = blockIdx.x >> 5;
  const int b0   = gid * 16;
  const int colbase = (s*4 + igrp)*16;
  const int col  = colbase + c;
  u32* cnt = cntbase + gid * 128;           // 512 B stride: no flag-line sharing
  u32* hb  = hbufbase + (size_t)gid * 8192; // two buffers of 16x256 u32 (=16x512 bf16)

  // --- weights into VGPRs (held for all steps) ---
  u16x8 wf[3][8];
  #pragma unroll
  for (int kk = 0; kk < 8; ++kk){
    const int ks = half*8 + kk;
    #pragma unroll
    for (int g = 0; g < 3; ++g){
      const int nt = g*32 + s*4 + igrp;
      wf[g][kk] = *(const u16x8*)(frag + (((size_t)ks*96 + nt)*64 + lane)*8);
    }
  }
  // --- h0 = 0 (+ col511 = 1.0 bias row), stored as packed u32 pairs via IF ---
  float hold[4] = {0.f, 0.f, 0.f, 0.f};
  if (half == 0){
    u32 me = (col == 511) ? 0x3F80u : 0u;
    u32 pr = __shfl_xor(me, 1, 64);
    if (!(c & 1)){
      u32 val = me | (pr << 16);
      #pragma unroll
      for (int r = 0; r < 4; ++r)
        __hip_atomic_store(hb + (q*4+r)*256 + (col>>1), val,
                           __ATOMIC_RELAXED, __HIP_MEMORY_SCOPE_AGENT);
    }
  }
  // --- prefetch gi for t=0 ---
  u16 giv[3][4];
  if (half == 0){
    #pragma unroll
    for (int g = 0; g < 3; ++g)
      #pragma unroll
      for (int r = 0; r < 4; ++r)
        giv[g][r] = __builtin_nontemporal_load(
            gi + ((size_t)(b0 + q*4 + r)*100 + 0)*1536 + g*512 + col);
  }
  __syncthreads();                          // drains vmcnt(0): h0 stores acked at IF
  if (tid == 0)
    __hip_atomic_fetch_add(cnt, 1u, __ATOMIC_RELAXED, __HIP_MEMORY_SCOPE_AGENT);

  #pragma unroll 1
  for (int t = 0; t < 100; ++t){
    if (tid == 0){
      const u32 target = 8u*(u32)(t+1);
      long guard = 0;
      while (__hip_atomic_load(cnt, __ATOMIC_RELAXED, __HIP_MEMORY_SCOPE_AGENT) < target){
        __builtin_amdgcn_s_sleep(1);
        if (++guard > (1L<<27)) break;      // hang-breaker (wrong data, not a hang)
      }
    }
    __syncthreads();
    const u64* cur64 = (const u64*)(hb + (t & 1)*4096);
    u32*       nxt   = hb + ((t+1) & 1)*4096;

    f32x4 acc0 = zero4(), acc1 = zero4(), acc2 = zero4();
    #pragma unroll
    for (int kk = 0; kk < 8; ++kk){
      const int ks = half*8 + kk;
      const u64* p = cur64 + c*128 + ks*8 + q*2;
      u64pair pp;
      pp.a = __hip_atomic_load(p,     __ATOMIC_RELAXED, __HIP_MEMORY_SCOPE_AGENT);
      pp.b = __hip_atomic_load(p + 1, __ATOMIC_RELAXED, __HIP_MEMORY_SCOPE_AGENT);
      bf16x8 af = __builtin_bit_cast(bf16x8, pp);
      acc0 = MFMA16x16(af, __builtin_bit_cast(bf16x8, wf[0][kk]), acc0);
      acc1 = MFMA16x16(af, __builtin_bit_cast(bf16x8, wf[1][kk]), acc1);
      acc2 = MFMA16x16(af, __builtin_bit_cast(bf16x8, wf[2][kk]), acc2);
    }
    if (half == 1){
      red[(igrp*3 + 0)*64 + lane] = acc0;
      red[(igrp*3 + 1)*64 + lane] = acc1;
      red[(igrp*3 + 2)*64 + lane] = acc2;
    }
    __syncthreads();
    u16 hvv[4];
    if (half == 0){
      const f32x4 p0 = red[(igrp*3+0)*64 + lane];
      const f32x4 p1 = red[(igrp*3+1)*64 + lane];
      const f32x4 p2 = red[(igrp*3+2)*64 + lane];
      #pragma unroll
      for (int r = 0; r < 4; ++r){
        float ar = acc0[r] + p0[r] + bf2f(giv[0][r]);
        float az = acc1[r] + p1[r] + bf2f(giv[1][r]);
        float an = acc2[r] + p2[r];
        float rr = fast_sigmoid(ar);
        float zz = fast_sigmoid(az);
        float nn = fast_tanh(bf2f(giv[2][r]) + rr*an);
        float h  = (1.f - zz)*nn + zz*hold[r];
        hold[r] = h;
        u16 hv16 = (col < 500) ? f2bf(h) : ((col == 511) ? (u16)0x3F80 : (u16)0);
        hvv[r] = hv16;
        u32 me = hv16;
        u32 pr = __shfl_xor(me, 1, 64);
        if (!(c & 1))
          __hip_atomic_store(nxt + (q*4+r)*256 + (col>>1), me | (pr << 16),
                             __ATOMIC_RELAXED, __HIP_MEMORY_SCOPE_AGENT);
      }
    }
    __syncthreads();                        // drains vmcnt(0): nxt stores acked at IF
    if (tid == 0)
      __hip_atomic_fetch_add(cnt, 1u, __ATOMIC_RELAXED, __HIP_MEMORY_SCOPE_AGENT);
    if (half == 0){
      #pragma unroll
      for (int r = 0; r < 4; ++r)
        __builtin_nontemporal_store(hvv[r],
            hout + ((size_t)(b0 + q*4 + r)*100 + t)*512 + col);
      if (t < 99){
        #pragma unroll
        for (int g = 0; g < 3; ++g)
          #pragma unroll
          for (int r = 0; r < 4; ++r)
            giv[g][r] = __builtin_nontemporal_load(
                gi + ((size_t)(b0 + q*4 + r)*100 + (t+1))*1536 + g*512 + col);
      }
    }
  }
}

// ---------------------------------------------------------------------------
// Post-net layer: out[51200][512] = pad( leaky_relu( A[51200][512] @ frag ) )
// ---------------------------------------------------------------------------
__global__ __launch_bounds__(512, 2) void gemm512(
    const u16* __restrict__ A, const u16* __restrict__ frag, u16* __restrict__ out)
{
  const int tid = threadIdx.x, lane = tid & 63, w = tid >> 6;
  const int q = lane >> 4, c = lane & 15;
  const int rb = w >> 1, nh = w & 1;
  const size_t rowbase = (size_t)blockIdx.x * 64 + rb * 16;
  f32x4 acc[16];
  #pragma unroll
  for (int i = 0; i < 16; ++i) acc[i] = zero4();
  const u16* Ar = A + (rowbase + c) * 512 + q * 8;
  #pragma unroll 1
  for (int ks = 0; ks < 16; ++ks){
    bf16x8 af = __builtin_bit_cast(bf16x8, *(const u16x8*)(Ar + ks * 32));
    #pragma unroll
    for (int i = 0; i < 16; ++i){
      const int nt = nh * 16 + i;
      bf16x8 bf = __builtin_bit_cast(bf16x8,
          *(const u16x8*)(frag + (((size_t)ks * 32 + nt) * 64 + lane) * 8));
      acc[i] = MFMA16x16(af, bf, acc[i]);
    }
  }
  #pragma unroll
  for (int i = 0; i < 16; ++i){
    const int col = (nh * 16 + i) * 16 + c;
    #pragma unroll
    for (int r = 0; r < 4; ++r){
      const size_t row = rowbase + q * 4 + r;
      float v = acc[i][r];
      v = fmaxf(v, 0.1f * v);
      u16 o = (col < 500) ? f2bf(v) : ((col == 511) ? (u16)0x3F80 : (u16)0);
      out[row * 512 + col] = o;
    }
  }
}

// ---------------------------------------------------------------------------
// hm precompute: hm[51200][8], cols 0..2 = h@zmW^T+zm_b, 3..5 = h@zsW^T+zs_b
// ---------------------------------------------------------------------------
__global__ __launch_bounds__(512, 2) void hm_kernel(
    const u16* __restrict__ A, const u16* __restrict__ zfrag, float* __restrict__ hm)
{
  const int tid = threadIdx.x, lane = tid & 63, w = tid >> 6;
  const int q = lane >> 4, c = lane & 15;
  const size_t rowbase = (size_t)blockIdx.x * 128 + w * 16;
  f32x4 acc = zero4();
  const u16* Ar = A + (rowbase + c) * 512 + q * 8;
  #pragma unroll 1
  for (int ks = 0; ks < 16; ++ks){
    bf16x8 af = __builtin_bit_cast(bf16x8, *(const u16x8*)(Ar + ks * 32));
    bf16x8 bf = __builtin_bit_cast(bf16x8,
        *(const u16x8*)(zfrag + (((size_t)ks * 64) + lane) * 8));
    acc = MFMA16x16(af, bf, acc);
  }
  if (c < 6){
    #pragma unroll
    for (int r = 0; r < 4; ++r)
      hm[(rowbase + q * 4 + r) * 8 + c] = acc[r];
  }
}

// ---------------------------------------------------------------------------
// Sequential latent scan: only the 3x3 z-feedback part (h-part precomputed).
// ---------------------------------------------------------------------------
__global__ void scan_kernel(const float* __restrict__ hm, const float* __restrict__ eps,
                            const float* __restrict__ zmW, const float* __restrict__ zsW,
                            float* __restrict__ zgen, float* __restrict__ zmu,
                            float* __restrict__ zstd)
{
  int b = blockIdx.x * blockDim.x + threadIdx.x;
  if (b >= 512) return;
  float Wm[3][3], Ws[3][3];
  #pragma unroll
  for (int j = 0; j < 3; ++j)
    #pragma unroll
    for (int k = 0; k < 3; ++k){
      Wm[j][k] = zmW[j * 503 + 500 + k];
      Ws[j][k] = zsW[j * 503 + 500 + k];
    }
  float z0 = 0.f, z1 = 0.f, z2 = 0.f;
  for (int t = 0; t < 100; ++t){
    size_t row = (size_t)b * 100 + t;
    const float* h = hm + row * 8;
    const float* e = eps + row * 3;
    float zn[3];
    #pragma unroll
    for (int j = 0; j < 3; ++j){
      float m_ = h[j]     + Wm[j][0]*z0 + Wm[j][1]*z1 + Wm[j][2]*z2;
      float p_ = h[3 + j] + Ws[j][0]*z0 + Ws[j][1]*z1 + Ws[j][2]*z2;
      float s_ = fast_softplus(p_) + 1e-4f;
      float zv = m_ + s_ * e[j];
      zgen[row * 3 + j] = zv;
      zmu [row * 3 + j] = m_;
      zstd[row * 3 + j] = s_;
      zn[j] = zv;
    }
    z0 = zn[0]; z1 = zn[1]; z2 = zn[2];
  }
}

// ---------------------------------------------------------------------------
// Planar flow (no scan feedback -> parallel over all 51200 (b,t))
// ---------------------------------------------------------------------------
__global__ void flow_kernel(const float* __restrict__ zgen, const float* __restrict__ fp,
                            float* __restrict__ zfin, float* __restrict__ ldj)
{
  int idx = blockIdx.x * blockDim.x + threadIdx.x;
  if (idx >= 51200) return;
  float z0 = zgen[idx*3+0], z1 = zgen[idx*3+1], z2 = zgen[idx*3+2];
  float ld = 0.f;
  #pragma unroll 1
  for (int l = 0; l < 20; ++l){
    const float* p = fp + l * 8;
    float lin = z0*p[0] + z1*p[1] + z2*p[2] + p[3];
    float tt = fast_tanh(lin);
    z0 += p[4]*tt; z1 += p[5]*tt; z2 += p[6]*tt;
    float det = 1.f + (1.f - tt*tt) * p[7];
    ld += __logf(fabsf(det) + 1e-7f);
  }
  zfin[idx*3+0] = z0; zfin[idx*3+1] = z1; zfin[idx*3+2] = z2;
  ldj[idx] = ld;
}

// ---------------------------------------------------------------------------
// Output heads: x_rec_mu = hd@xmW^T+xm_b ; x_rec_std = softplus(hd@xsW^T+xs_b)+1e-4
// ---------------------------------------------------------------------------
__global__ __launch_bounds__(512, 2) void heads_kernel(
    const u16* __restrict__ A, const u16* __restrict__ hfrag,
    float* __restrict__ out_mu, float* __restrict__ out_std)
{
  const int tid = threadIdx.x, lane = tid & 63, w = tid >> 6;
  const int q = lane >> 4, c = lane & 15;
  const size_t rowbase = (size_t)blockIdx.x * 128 + w * 16;
  f32x4 acc[6];
  #pragma unroll
  for (int i = 0; i < 6; ++i) acc[i] = zero4();
  const u16* Ar = A + (rowbase + c) * 512 + q * 8;
  #pragma unroll 1
  for (int ks = 0; ks < 16; ++ks){
    bf16x8 af = __builtin_bit_cast(bf16x8, *(const u16x8*)(Ar + ks * 32));
    #pragma unroll
    for (int i = 0; i < 6; ++i){
      bf16x8 bf = __builtin_bit_cast(bf16x8,
          *(const u16x8*)(hfrag + (((size_t)ks * 6 + i) * 64 + lane) * 8));
      acc[i] = MFMA16x16(af, bf, acc[i]);
    }
  }
  #pragma unroll
  for (int i = 0; i < 6; ++i){
    const int cc  = i * 16 + c;
    const int grp = cc / 48;
    const int col = cc - grp * 48;
    if (col < 38){
      #pragma unroll
      for (int r = 0; r < 4; ++r){
        const size_t row = rowbase + q * 4 + r;
        float v = acc[i][r];
        if (grp == 0) out_mu[row * 38 + col] = v;
        else          out_std[row * 38 + col] = fast_softplus(v) + 1e-4f;
      }
    }
  }
}

// ---------------------------------------------------------------------------
extern "C" void kernel_launch(void* const* d_in, const int* in_sizes, int n_in,
                              void* d_out, int out_size, void* d_ws, size_t ws_size,
                              hipStream_t stream)
{
  const float* x       = (const float*)d_in[0];
  const float* eps     = (const float*)d_in[1];
  const float* enc_Wih = (const float*)d_in[2];
  const float* enc_Whh = (const float*)d_in[3];
  const float* enc_bih = (const float*)d_in[4];
  const float* enc_bhh = (const float*)d_in[5];
  const float* enc_W1  = (const float*)d_in[6];
  const float* enc_b1  = (const float*)d_in[7];
  const float* enc_W2  = (const float*)d_in[8];
  const float* enc_b2  = (const float*)d_in[9];
  const float* zm_W    = (const float*)d_in[10];
  const float* zm_b    = (const float*)d_in[11];
  const float* zs_W    = (const float*)d_in[12];
  const float* zs_b    = (const float*)d_in[13];
  const float* flow_w  = (const float*)d_in[14];
  const float* flow_b  = (const float*)d_in[15];
  const float* flow_u  = (const float*)d_in[16];
  const float* dec_Wih = (const float*)d_in[17];
  const float* dec_Whh = (const float*)d_in[18];
  const float* dec_bih = (const float*)d_in[19];
  const float* dec_bhh = (const float*)d_in[20];
  const float* dec_W1  = (const float*)d_in[21];
  const float* dec_b1  = (const float*)d_in[22];
  const float* dec_W2  = (const float*)d_in[23];
  const float* dec_b2  = (const float*)d_in[24];
  const float* xm_W    = (const float*)d_in[25];
  const float* xm_b    = (const float*)d_in[26];
  const float* xs_W    = (const float*)d_in[27];
  const float* xs_b    = (const float*)d_in[28];
  (void)in_sizes; (void)n_in; (void)out_size; (void)ws_size;

  float* out    = (float*)d_out;
  float* r_mu   = out;                 // [512,100,38]
  float* r_std  = out + 1945600;       // [512,100,38]
  float* r_zgen = out + 3891200;       // [512,100,3]
  float* r_zfin = out + 4044800;       // [512,100,3]
  float* r_zmu  = out + 4198400;       // [512,100,3]
  float* r_zstd = out + 4352000;       // [512,100,3]
  float* r_ldj  = out + 4505600;       // [512,100,1]

  char* ws = (char*)d_ws;
  size_t off = 0;
  auto alloc = [&](size_t bytes)->char*{
    char* p = ws + off;
    off += (bytes + 255) & ~(size_t)255;
    return p;
  };
  u16* H1    = (u16*)alloc((size_t)51200*512*2);     // GRU hidden states
  u16* BIG   = (u16*)alloc((size_t)51200*1536*2);    // gi buffer; aliased as P1/P2
  u16* P1    = BIG;                                  // [51200][512]
  u16* P2    = BIG + (size_t)51200*512;              // [51200][512]
  u16* ENCF  = (u16*)alloc((size_t)16*96*512*2);
  u16* DECF  = (u16*)alloc((size_t)16*96*512*2);
  u16* EGIF  = (u16*)alloc((size_t)2*96*512*2);
  u16* PF0   = (u16*)alloc((size_t)16*32*512*2);
  u16* PF1   = (u16*)alloc((size_t)16*32*512*2);
  u16* PF2   = (u16*)alloc((size_t)16*32*512*2);
  u16* PF3   = (u16*)alloc((size_t)16*32*512*2);
  u16* ZFR   = (u16*)alloc((size_t)16*1*512*2);
  u16* HFR   = (u16*)alloc((size_t)16*6*512*2);
  float* FPP = (float*)alloc((size_t)20*8*4);
  float* HM  = (float*)alloc((size_t)51200*8*4);
  u32* HBUF  = (u32*)alloc((size_t)32*2*16*512*2);   // h exchange (u32-packed bf16 pairs)
  u32* CNT   = (u32*)alloc((size_t)2*32*128*4);      // 512 B per group counter, enc+dec

  // --- sync counters + weight prep ---
  hipMemsetAsync(CNT, 0, 2*32*128*4, stream);
  build_frag<<<3072,256,0,stream>>>(ENCF,0,16,96,enc_Whh,enc_bhh,nullptr,nullptr);
  build_frag<<<3072,256,0,stream>>>(DECF,0,16,96,dec_Whh,dec_bhh,nullptr,nullptr);
  build_frag<<<384,256,0,stream>>>(EGIF,5,2,96,enc_Wih,nullptr,nullptr,nullptr);
  build_frag<<<1024,256,0,stream>>>(PF0,2,16,32,enc_W1,enc_b1,nullptr,nullptr);
  build_frag<<<1024,256,0,stream>>>(PF1,2,16,32,enc_W2,enc_b2,nullptr,nullptr);
  build_frag<<<1024,256,0,stream>>>(PF2,2,16,32,dec_W1,dec_b1,nullptr,nullptr);
  build_frag<<<1024,256,0,stream>>>(PF3,2,16,32,dec_W2,dec_b2,nullptr,nullptr);
  build_frag<<<32,256,0,stream>>>(ZFR,3,16,1,zm_W,zm_b,zs_W,zs_b);
  build_frag<<<192,256,0,stream>>>(HFR,4,16,6,xm_W,xm_b,xs_W,xs_b);
  flow_prep<<<1,64,0,stream>>>(flow_w,flow_b,flow_u,FPP);

  // --- encoder ---
  gi_enc_kernel<<<1600,512,0,stream>>>(x, EGIF, enc_bih, BIG);
  gru2_kernel<<<256,512,0,stream>>>(ENCF, BIG, HBUF, H1, CNT);
  gemm512<<<800,512,0,stream>>>(H1, PF0, P1);          // gi dead; BIG reused as P1/P2
  gemm512<<<800,512,0,stream>>>(P1, PF1, P2);
  hm_kernel<<<400,512,0,stream>>>(P2, ZFR, HM);

  // --- latent scan + planar flow ---
  scan_kernel<<<2,256,0,stream>>>(HM, eps, zm_W, zs_W, r_zgen, r_zmu, r_zstd);
  flow_kernel<<<200,256,0,stream>>>(r_zgen, FPP, r_zfin, r_ldj);

  // --- decoder ---
  gi_dec_kernel<<<38400,256,0,stream>>>(r_zfin, dec_Wih, dec_bih, BIG);  // P1/P2 dead
  gru2_kernel<<<256,512,0,stream>>>(DECF, BIG, HBUF, H1, CNT + 32*128);
  gemm512<<<800,512,0,stream>>>(H1, PF2, P1);          // gi dead again
  gemm512<<<800,512,0,stream>>>(P1, PF3, P2);
  heads_kernel<<<400,512,0,stream>>>(P2, HFR, r_mu, r_std);
}